// Round 1
// baseline (105.792 us; speedup 1.0000x reference)
//
#include <hip/hip_runtime.h>
#include <math.h>

#define MAXGT 128
#define POS_LIMIT 128
#define TOTAL 256

// -------- shared device helpers --------

__device__ __forceinline__ void stage_gt(const float* __restrict__ gt, int M,
                                         float4* sbox, float* sarea) {
#pragma clang fp contract(off)
    int tid = threadIdx.x;
    if (tid < M) {
        float4 b = ((const float4*)gt)[tid];
        sbox[tid] = b;
        sarea[tid] = (b.z - b.x) * (b.w - b.y);
    }
    __syncthreads();
}

// argmax_j IoU(a, gt_j) — replicates numpy fp32 op order exactly (no fma
// contraction, IEEE divide, strict > keeps first occurrence of max like
// np.argmax).
__device__ __forceinline__ int iou_argmax(float4 a, int M,
                                          const float4* sbox, const float* sarea) {
#pragma clang fp contract(off)
    float areaA = (a.z - a.x) * (a.w - a.y);
    float best = -INFINITY;
    int bi = 0;
    for (int j = 0; j < M; ++j) {
        float4 b = sbox[j];
        float lt0 = fmaxf(a.x, b.x);
        float lt1 = fmaxf(a.y, b.y);
        float rb0 = fminf(a.z, b.z);
        float rb1 = fminf(a.w, b.w);
        float w = fmaxf(rb0 - lt0, 0.0f);
        float h = fmaxf(rb1 - lt1, 0.0f);
        float inter = w * h;
        float iou = inter / ((areaA + sarea[j]) - inter);
        if (iou > best) { best = iou; bi = j; }
    }
    return bi;
}

// -------- kernel 1: per-block pos/neg counts --------

__global__ void __launch_bounds__(256)
k_count(const float* __restrict__ anchors, const float* __restrict__ gt,
        int N, int M, int* __restrict__ blockPos, int* __restrict__ blockNeg) {
    __shared__ float4 sbox[MAXGT];
    __shared__ float sarea[MAXGT];
    __shared__ int wp[4], wn[4];
    stage_gt(gt, M, sbox, sarea);

    int tid = threadIdx.x;
    int i = blockIdx.x * 256 + tid;
    int posf = 0, negf = 0;
    if (i < N) {
        float4 a = ((const float4*)anchors)[i];
        int bi = iou_argmax(a, M, sbox, sarea);
        posf = (bi >= 1);
        negf = (bi == 0);
    }
    unsigned long long pm = __ballot(posf);
    unsigned long long nm = __ballot(negf);
    int lane = tid & 63, wave = tid >> 6;
    if (lane == 0) { wp[wave] = __popcll(pm); wn[wave] = __popcll(nm); }
    __syncthreads();
    if (tid == 0) {
        blockPos[blockIdx.x] = wp[0] + wp[1] + wp[2] + wp[3];
        blockNeg[blockIdx.x] = wn[0] + wn[1] + wn[2] + wn[3];
    }
}

// -------- kernel 2: exclusive scan of block counts --------

__global__ void __launch_bounds__(256)
k_scan(const int* __restrict__ blockPos, const int* __restrict__ blockNeg,
       int* __restrict__ posBase, int* __restrict__ negBase,
       int nb, int* __restrict__ curPosOut) {
    __shared__ int sp[256], sn[256];
    int tid = threadIdx.x;
    int chunk = (nb + 255) / 256;
    int s0 = tid * chunk;
    int lp = 0, ln = 0;
    for (int k = 0; k < chunk; ++k) {
        int idx = s0 + k;
        if (idx < nb) { lp += blockPos[idx]; ln += blockNeg[idx]; }
    }
    sp[tid] = lp; sn[tid] = ln;
    __syncthreads();
    // Hillis-Steele inclusive scan over 256 partials
    for (int off = 1; off < 256; off <<= 1) {
        int vp = (tid >= off) ? sp[tid - off] : 0;
        int vn = (tid >= off) ? sn[tid - off] : 0;
        __syncthreads();
        sp[tid] += vp; sn[tid] += vn;
        __syncthreads();
    }
    int basep = (tid == 0) ? 0 : sp[tid - 1];
    int basen = (tid == 0) ? 0 : sn[tid - 1];
    for (int k = 0; k < chunk; ++k) {
        int idx = s0 + k;
        if (idx < nb) {
            posBase[idx] = basep; negBase[idx] = basen;
            basep += blockPos[idx]; basen += blockNeg[idx];
        }
    }
    if (tid == 255) {
        *curPosOut = min(sp[255], POS_LIMIT);
    }
}

// -------- kernel 3: scatter first-K pos/neg anchor indices --------

__global__ void __launch_bounds__(256)
k_select(const float* __restrict__ anchors, const float* __restrict__ gt,
         int N, int M, const int* __restrict__ posBase, const int* __restrict__ negBase,
         int* __restrict__ pos_sel, int* __restrict__ pos_gt,
         int* __restrict__ neg_sel, int* __restrict__ neg_gt) {
    int b = blockIdx.x;
    int pb = posBase[b], nbse = negBase[b];
    if (pb >= POS_LIMIT && nbse >= TOTAL) return;  // block-uniform early exit

    __shared__ float4 sbox[MAXGT];
    __shared__ float sarea[MAXGT];
    __shared__ int wpo[4], wno[4];
    stage_gt(gt, M, sbox, sarea);

    int tid = threadIdx.x;
    int i = b * 256 + tid;
    int posf = 0, negf = 0, gidx = 0;
    if (i < N) {
        float4 a = ((const float4*)anchors)[i];
        gidx = iou_argmax(a, M, sbox, sarea);
        posf = (gidx >= 1);
        negf = (gidx == 0);
    }
    unsigned long long pm = __ballot(posf);
    unsigned long long nm = __ballot(negf);
    int lane = tid & 63, wave = tid >> 6;
    if (lane == 0) { wpo[wave] = __popcll(pm); wno[wave] = __popcll(nm); }
    __syncthreads();
    int poff = 0, noff = 0;
    for (int w = 0; w < wave; ++w) { poff += wpo[w]; noff += wno[w]; }
    unsigned long long ltmask = (1ull << lane) - 1ull;
    int prank = pb + poff + __popcll(pm & ltmask);
    int nrank = nbse + noff + __popcll(nm & ltmask);
    if (posf && prank < POS_LIMIT) { pos_sel[prank] = i; pos_gt[prank] = gidx; }
    if (negf && nrank < TOTAL)     { neg_sel[nrank] = i; neg_gt[nrank] = gidx; }
}

// -------- kernel 4: losses over the 256 selected samples --------

__global__ void __launch_bounds__(256)
k_loss(const float* __restrict__ score, const float* __restrict__ pred,
       const float* __restrict__ anchors, const float* __restrict__ gt,
       const int* __restrict__ curPosPtr,
       const int* __restrict__ pos_sel, const int* __restrict__ pos_gt,
       const int* __restrict__ neg_sel, const int* __restrict__ neg_gt,
       float* __restrict__ out) {
#pragma clang fp contract(off)
    int tid = threadIdx.x;
    int curPos = *curPosPtr;
    int sel, label, g;
    if (tid < curPos) { sel = pos_sel[tid]; g = pos_gt[tid]; label = 1; }
    else              { int k = tid - curPos; sel = neg_sel[k]; g = neg_gt[k]; label = 0; }

    // classification: -log_softmax(score[sel])[label]
    float s0 = score[2 * sel], s1 = score[2 * sel + 1];
    float m = fmaxf(s0, s1);
    float sh0 = s0 - m, sh1 = s1 - m;
    float lse = logf(expf(sh0) + expf(sh1));
    float cls = -((label ? sh1 : sh0) - lse);

    // regression: smooth-L1 on encoded targets, inside weight = label
    float reg = 0.0f;
    if (label) {
        float4 a = ((const float4*)anchors)[sel];
        float4 gb = ((const float4*)gt)[g];
        float aw = a.z - a.x, ah = a.w - a.y;
        float acx = a.x + 0.5f * aw, acy = a.y + 0.5f * ah;
        float gw = gb.z - gb.x, gh = gb.w - gb.y;
        float gcx = gb.x + 0.5f * gw, gcy = gb.y + 0.5f * gh;
        float4 p = ((const float4*)pred)[sel];
        float d0 = p.x - (gcx - acx) / aw;
        float d1 = p.y - (gcy - acy) / ah;
        float d2 = p.z - logf(gw / aw);
        float d3 = p.w - logf(gh / ah);
        float a0 = fabsf(d0), a1 = fabsf(d1), a2 = fabsf(d2), a3 = fabsf(d3);
        float sm0 = (a0 < 1.0f) ? 0.5f * d0 * d0 : a0 - 0.5f;
        float sm1 = (a1 < 1.0f) ? 0.5f * d1 * d1 : a1 - 0.5f;
        float sm2 = (a2 < 1.0f) ? 0.5f * d2 * d2 : a2 - 0.5f;
        float sm3 = (a3 < 1.0f) ? 0.5f * d3 * d3 : a3 - 0.5f;
        reg = 2.0f * (sm0 + sm1 + sm2 + sm3);
    }

    // block reduce (wave shuffle + LDS across 4 waves)
    for (int off = 32; off > 0; off >>= 1) {
        cls += __shfl_down(cls, off);
        reg += __shfl_down(reg, off);
    }
    __shared__ float rc[4], rr[4];
    int lane = tid & 63, wave = tid >> 6;
    if (lane == 0) { rc[wave] = cls; rr[wave] = reg; }
    __syncthreads();
    if (tid == 0) {
        out[0] = (rc[0] + rc[1] + rc[2] + rc[3]) * (1.0f / 256.0f);  // CLS_W = 1
        out[1] = (rr[0] + rr[1] + rr[2] + rr[3]) * (1.0f / 256.0f);  // REG_W folded (2.f)
    }
}

// -------- host launch --------

extern "C" void kernel_launch(void* const* d_in, const int* in_sizes, int n_in,
                              void* d_out, int out_size, void* d_ws, size_t ws_size,
                              hipStream_t stream) {
    const float* rpn_score = (const float*)d_in[0];
    const float* rpn_pred  = (const float*)d_in[1];
    const float* anchors   = (const float*)d_in[2];
    const float* gt        = (const float*)d_in[3];
    int N = in_sizes[2] / 4;
    int M = in_sizes[3] / 4;
    if (M > MAXGT) M = MAXGT;  // setup uses M=100

    int nb = (N + 255) / 256;

    // workspace layout (all int32)
    int* w = (int*)d_ws;
    int* blockPos = w;            w += nb;
    int* blockNeg = w;            w += nb;
    int* posBase  = w;            w += nb;
    int* negBase  = w;            w += nb;
    int* curPos   = w;            w += 1;
    int* pos_sel  = w;            w += POS_LIMIT;
    int* pos_gt   = w;            w += POS_LIMIT;
    int* neg_sel  = w;            w += TOTAL;
    int* neg_gt   = w;            w += TOTAL;

    k_count<<<nb, 256, 0, stream>>>(anchors, gt, N, M, blockPos, blockNeg);
    k_scan<<<1, 256, 0, stream>>>(blockPos, blockNeg, posBase, negBase, nb, curPos);
    k_select<<<nb, 256, 0, stream>>>(anchors, gt, N, M, posBase, negBase,
                                     pos_sel, pos_gt, neg_sel, neg_gt);
    k_loss<<<1, 256, 0, stream>>>(rpn_score, rpn_pred, anchors, gt, curPos,
                                  pos_sel, pos_gt, neg_sel, neg_gt, (float*)d_out);
}